// Round 10
// baseline (63.317 us; speedup 1.0000x reference)
//
#include <hip/hip_runtime.h>

#define NN 2048
#define KK 32

typedef __attribute__((ext_vector_type(8))) short short8;   // 8 x bf16
typedef __attribute__((ext_vector_type(4))) float f32x4;

// workspace (bytes):
//  u_pk   : [2048 j][32 b][32 k][8 zp] u32 (bf16 z-pairs) 64 MiB @ 0
//  t_part3: [8 jsl][8192 col] float2                     512 KiB @ 67108864
//  t      : [32 b][32 k][16 z] f32                        64 KiB @ 67633152
//  s_part : [32 b][64 jc][512] f32                         4 MiB @ 67698688
#define WS_U     0UL
#define WS_TP3   67108864UL
#define WS_T     67633152UL
#define WS_SPART 67698688UL
#define WS_NEED  71892992UL

__device__ __forceinline__ float bf_lo(unsigned v) { return __uint_as_float(v << 16); }
__device__ __forceinline__ float bf_hi(unsigned v) { return __uint_as_float(v & 0xffff0000u); }
__device__ __forceinline__ unsigned pack_bf16(float a, float b) {
    unsigned ua = __float_as_uint(a), ub = __float_as_uint(b);
    return ((ua + 0x8000u) >> 16) | ((ub + 0x8000u) & 0xffff0000u);
}
__device__ __forceinline__ short8 pack8(const float* r) {
    short8 o;
#pragma unroll
    for (int e = 0; e < 8; ++e)
        o[e] = (short)(unsigned short)((__float_as_uint(r[e]) + 0x8000u) >> 16);
    return o;
}
__device__ __forceinline__ short8 sel8(bool keep, short8 v) {
    union { short8 s; unsigned u[4]; } a, b;
    a.s = v;
#pragma unroll
    for (int i = 0; i < 4; ++i) b.u[i] = keep ? a.u[i] : 0u;
    return b.s;
}

// ---------------- kA2: u only (bf16), via MFMA + LDS transpose --------------
// grid 1024 (2 j / block), block 512 = 8 waves; wave wv owns k = wv*4..+4.
// A = w fragment (M=z), B = x fragment (N=b); C: row=z (regs), col=b (lanes).
// Both jj tiles packed to LDS first, ONE lgkm drain, then 16 coalesced
// 512B store instrs (4 x 128B fully-covered segments each).
__global__ __launch_bounds__(512)
void kA2(const float* __restrict__ x, const float* __restrict__ w,
         unsigned* __restrict__ u_pk)
{
    __shared__ uint2 xfer[8][2][32][17];   // per-wave, per-jj 32b x 16 + pad
    const int tid = threadIdx.x;
    const int wv = tid >> 6, l = tid & 63;
    const int c16 = l & 15, g = l >> 4;
    const int jl = g >> 1, ih = g & 1;
    const int j0 = blockIdx.x * 2;
    const int jp = j0 + jl;

    // A fragments (w): strided dword loads, z = c16
    short8 Wf[4];
#pragma unroll
    for (int ckl = 0; ckl < 4; ++ckl) {
        const int k = wv * 4 + ckl;
        const float* wp = w + ((size_t)k * NN + jp) * 256 + ih * 128 + c16;
        float br[8];
#pragma unroll
        for (int e = 0; e < 8; ++e) br[e] = wp[e * 16];
        Wf[ckl] = pack8(br);
    }
    // B fragments (x): b = bn*16 + c16, 8 contiguous floats
    short8 Xf[2];
#pragma unroll
    for (int bn = 0; bn < 2; ++bn) {
        const float* xp = x + ((size_t)(bn * 16 + c16) * NN + jp) * 16 + ih * 8;
        float ar[8];
        float4 v0 = *reinterpret_cast<const float4*>(xp);
        float4 v1 = *reinterpret_cast<const float4*>(xp + 4);
        ar[0]=v0.x; ar[1]=v0.y; ar[2]=v0.z; ar[3]=v0.w;
        ar[4]=v1.x; ar[5]=v1.y; ar[6]=v1.z; ar[7]=v1.w;
        Xf[bn] = pack8(ar);
    }

    // MFMA + pack both jj tiles into LDS
#pragma unroll
    for (int jj = 0; jj < 2; ++jj) {
        const bool keep = (jl == jj);
        const f32x4 zero = (f32x4){0.f, 0.f, 0.f, 0.f};
        uint2* xw = &xfer[wv][jj][0][0];
#pragma unroll
        for (int ckl = 0; ckl < 4; ++ckl) {
            const short8 wsel = sel8(keep, Wf[ckl]);
#pragma unroll
            for (int bn = 0; bn < 2; ++bn) {
                f32x4 Cj = __builtin_amdgcn_mfma_f32_16x16x32_bf16(
                    wsel, Xf[bn], zero, 0, 0, 0);
                uint2 o;
                o.x = pack_bf16(Cj[0], Cj[1]);
                o.y = pack_bf16(Cj[2], Cj[3]);
                xw[(bn * 16 + c16) * 17 + ckl * 4 + g] = o;
            }
        }
    }

    // single drain (compiler inserts lgkmcnt before first read), 16 stores
#pragma unroll
    for (int jj = 0; jj < 2; ++jj) {
        const uint2* xw = &xfer[wv][jj][0][0];
        uint2* ubase = reinterpret_cast<uint2*>(u_pk)
                     + (size_t)(j0 + jj) * 4096 + wv * 16 + c16;
#pragma unroll
        for (int m = 0; m < 8; ++m) {
            uint2 v = xw[(m * 4 + g) * 17 + c16];
            ubase[m * 512 + g * 128] = v;
        }
    }
}

// ---------------- kt_u: t partials = sum over j-slices of u_pk --------------
// grid 256 (= 32 col-chunks x 8 j-slices), block 1024: js4 = tid>>8, cl = tid&255.
__global__ __launch_bounds__(1024)
void kt_u(const unsigned* __restrict__ u_pk, float2* __restrict__ t_part3)
{
    __shared__ float2 red[4][256];
    const int tid = threadIdx.x;
    const int js4 = tid >> 8, cl = tid & 255;
    const int cc  = blockIdx.x & 31, jsl = blockIdx.x >> 5;
    const int col = cc * 256 + cl;

    const unsigned* up = u_pk + (size_t)(jsl * 256 + js4) * 8192 + col;
    float a_lo = 0.f, a_hi = 0.f;
#pragma unroll 4
    for (int q = 0; q < 64; ++q) {
        unsigned v = up[(size_t)q * 4 * 8192];
        a_lo += bf_lo(v); a_hi += bf_hi(v);
    }
    red[js4][cl] = make_float2(a_lo, a_hi);
    __syncthreads();
    if (tid < 256) {
        float2 r0 = red[0][tid], r1 = red[1][tid], r2 = red[2][tid], r3 = red[3][tid];
        float2 o;
        o.x = (r0.x + r1.x) + (r2.x + r3.x);
        o.y = (r0.y + r1.y) + (r2.y + r3.y);
        t_part3[(size_t)jsl * 8192 + cc * 256 + tid] = o;
    }
}

// ---------------- kt2b: reduce 8 slices -> t[b][k][z] -----------------------
__global__ __launch_bounds__(256)
void kt2b(const float2* __restrict__ t_part3, float* __restrict__ t)
{
    const int cidx = blockIdx.x * 256 + threadIdx.x;   // [0, 8192)
    float2 a = make_float2(0.f, 0.f);
#pragma unroll
    for (int sl = 0; sl < 8; ++sl) {
        float2 v = t_part3[(size_t)sl * 8192 + cidx];
        a.x += v.x; a.y += v.y;
    }
    const int b = cidx >> 8, k = (cidx >> 3) & 31, zp = cidx & 7;
    t[(size_t)(b * 32 + k) * 16 + zp * 2]     = a.x;
    t[(size_t)(b * 32 + k) * 16 + zp * 2 + 1] = a.y;
}

// ---------------- kB2: logits + softmax + bias + s-partials (VALU only) -----
// grid 2048 (= 32 b * 64 jc), block 256: k = tid&31, jl = tid>>5.
__global__ __launch_bounds__(256)
void kB2(const unsigned* __restrict__ u_pk, const float* __restrict__ t,
         const float* __restrict__ bias, float* __restrict__ s_part)
{
    __shared__ float lc_lds[32][33];
    __shared__ float s_lds[8][32][16];
    const int tid = threadIdx.x;
    const int k   = tid & 31;
    const int jl  = tid >> 5;
    const int b   = blockIdx.x >> 6;
    const int jc  = blockIdx.x & 63;

    float tr[16];
    const float4* tp = reinterpret_cast<const float4*>(t + ((size_t)b * KK + k) * 16);
#pragma unroll
    for (int q = 0; q < 4; ++q) {
        float4 v = tp[q];
        tr[4 * q + 0] = v.x; tr[4 * q + 1] = v.y; tr[4 * q + 2] = v.z; tr[4 * q + 3] = v.w;
    }

    uint4 ua[4], ud[4];
#pragma unroll
    for (int jj = 0; jj < 4; ++jj) {
        const int jL = jj * 8 + jl;
        const int jg = jc * 32 + jL;
        const uint4* up = reinterpret_cast<const uint4*>(u_pk)
                        + (((size_t)jg * 32 + b) * 32 + k) * 2;
        ua[jj] = up[0]; ud[jj] = up[1];
        float a0 = 0.f, a1 = 0.f;
        a0 = fmaf(bf_lo(ua[jj].x), tr[0],  a0); a1 = fmaf(bf_hi(ua[jj].x), tr[1],  a1);
        a0 = fmaf(bf_lo(ua[jj].y), tr[2],  a0); a1 = fmaf(bf_hi(ua[jj].y), tr[3],  a1);
        a0 = fmaf(bf_lo(ua[jj].z), tr[4],  a0); a1 = fmaf(bf_hi(ua[jj].z), tr[5],  a1);
        a0 = fmaf(bf_lo(ua[jj].w), tr[6],  a0); a1 = fmaf(bf_hi(ua[jj].w), tr[7],  a1);
        a0 = fmaf(bf_lo(ud[jj].x), tr[8],  a0); a1 = fmaf(bf_hi(ud[jj].x), tr[9],  a1);
        a0 = fmaf(bf_lo(ud[jj].y), tr[10], a0); a1 = fmaf(bf_hi(ud[jj].y), tr[11], a1);
        a0 = fmaf(bf_lo(ud[jj].z), tr[12], a0); a1 = fmaf(bf_hi(ud[jj].z), tr[13], a1);
        a0 = fmaf(bf_lo(ud[jj].w), tr[14], a0); a1 = fmaf(bf_hi(ud[jj].w), tr[15], a1);
        lc_lds[jL][k] = a0 + a1;
    }
    __syncthreads();

    {
        const int jq = tid >> 3, kq = tid & 7;
        float lv[4];
#pragma unroll
        for (int m = 0; m < 4; ++m) lv[m] = lc_lds[jq][kq * 4 + m];
        float pm = fmaxf(fmaxf(lv[0], lv[1]), fmaxf(lv[2], lv[3]));
        pm = fmaxf(pm, __shfl_xor(pm, 1));
        pm = fmaxf(pm, __shfl_xor(pm, 2));
        pm = fmaxf(pm, __shfl_xor(pm, 4));
        float ev[4], ps = 0.f;
#pragma unroll
        for (int m = 0; m < 4; ++m) { ev[m] = __expf((lv[m] - pm) * 0.25f); ps += ev[m]; }
        ps += __shfl_xor(ps, 1);
        ps += __shfl_xor(ps, 2);
        ps += __shfl_xor(ps, 4);
        const float inv = 1.f / ps;
        const int jg = jc * 32 + jq;
#pragma unroll
        for (int m = 0; m < 4; ++m)
            lv[m] = ev[m] * inv + bias[(size_t)(kq * 4 + m) * NN + jg];
        __syncthreads();
#pragma unroll
        for (int m = 0; m < 4; ++m) lc_lds[jq][kq * 4 + m] = lv[m];
    }
    __syncthreads();

    float sacc[16];
#pragma unroll
    for (int z = 0; z < 16; ++z) sacc[z] = 0.f;
#pragma unroll
    for (int jj = 0; jj < 4; ++jj) {
        const float cv = lc_lds[jj * 8 + jl][k];
        const uint4 a = ua[jj], d = ud[jj];
        sacc[0]  = fmaf(cv, bf_lo(a.x), sacc[0]);  sacc[1]  = fmaf(cv, bf_hi(a.x), sacc[1]);
        sacc[2]  = fmaf(cv, bf_lo(a.y), sacc[2]);  sacc[3]  = fmaf(cv, bf_hi(a.y), sacc[3]);
        sacc[4]  = fmaf(cv, bf_lo(a.z), sacc[4]);  sacc[5]  = fmaf(cv, bf_hi(a.z), sacc[5]);
        sacc[6]  = fmaf(cv, bf_lo(a.w), sacc[6]);  sacc[7]  = fmaf(cv, bf_hi(a.w), sacc[7]);
        sacc[8]  = fmaf(cv, bf_lo(d.x), sacc[8]);  sacc[9]  = fmaf(cv, bf_hi(d.x), sacc[9]);
        sacc[10] = fmaf(cv, bf_lo(d.y), sacc[10]); sacc[11] = fmaf(cv, bf_hi(d.y), sacc[11]);
        sacc[12] = fmaf(cv, bf_lo(d.z), sacc[12]); sacc[13] = fmaf(cv, bf_hi(d.z), sacc[13]);
        sacc[14] = fmaf(cv, bf_lo(d.w), sacc[14]); sacc[15] = fmaf(cv, bf_hi(d.w), sacc[15]);
    }

#pragma unroll
    for (int q = 0; q < 4; ++q)
        *reinterpret_cast<float4*>(&s_lds[jl][k][q * 4]) =
            make_float4(sacc[q * 4], sacc[q * 4 + 1], sacc[q * 4 + 2], sacc[q * 4 + 3]);
    __syncthreads();
    {
        const int kk = tid >> 3, zp = tid & 7;
        float2 o; o.x = 0.f; o.y = 0.f;
#pragma unroll
        for (int l2 = 0; l2 < 8; ++l2) {
            o.x += s_lds[l2][kk][2 * zp];
            o.y += s_lds[l2][kk][2 * zp + 1];
        }
        reinterpret_cast<float2*>(s_part)[((size_t)b * 64 + jc) * 256 + kk * 8 + zp] = o;
    }
}

// ---------------- k4: reduce jc slices + squash (float4) --------------------
__global__ __launch_bounds__(256)
void k4_squash(const float* __restrict__ s_part, float* __restrict__ out)
{
    const int idx4 = blockIdx.x * 256 + threadIdx.x;   // 4096 float4s
    const int b = idx4 >> 7, loc4 = idx4 & 127;        // loc4 = k*4 + zq
    const float4* p = reinterpret_cast<const float4*>(s_part) + (size_t)b * 8192 + loc4;
    float4 s = make_float4(0.f, 0.f, 0.f, 0.f);
#pragma unroll 8
    for (int jc = 0; jc < 64; ++jc) {
        float4 v = p[jc * 128];
        s.x += v.x; s.y += v.y; s.z += v.z; s.w += v.w;
    }
    float ss = s.x * s.x + s.y * s.y + s.z * s.z + s.w * s.w;
    ss += __shfl_xor(ss, 1);   // lanes zq 0..3 of same (b,k)
    ss += __shfl_xor(ss, 2);
    const float n = sqrtf(ss);
    const float sc = (1.f - 1.f / (__expf(n) + 1e-20f)) / (n + 1e-20f);
    float4 o; o.x = s.x * sc; o.y = s.y * sc; o.z = s.z * sc; o.w = s.w * sc;
    reinterpret_cast<float4*>(out)[idx4] = o;
}

// sentinel if workspace too small
__global__ void k_sentinel(float* __restrict__ out)
{
    out[blockIdx.x * 256 + threadIdx.x] = 12345.0f;
}

extern "C" void kernel_launch(void* const* d_in, const int* in_sizes, int n_in,
                              void* d_out, int out_size, void* d_ws, size_t ws_size,
                              hipStream_t stream)
{
    const float* x    = (const float*)d_in[0];
    const float* w    = (const float*)d_in[1];
    const float* bias = (const float*)d_in[2];
    float* out        = (float*)d_out;

    char* ws = (char*)d_ws;
    if (ws_size < WS_NEED) {
        k_sentinel<<<dim3(64), dim3(256), 0, stream>>>(out);
        return;
    }
    unsigned* u_pk   = (unsigned*)(ws + WS_U);
    float2*   t_part3= (float2*)(ws + WS_TP3);
    float*    t      = (float*)(ws + WS_T);
    float*    s_part = (float*)(ws + WS_SPART);

    kA2      <<<dim3(1024), dim3(512),  0, stream>>>(x, w, u_pk);
    kt_u     <<<dim3(256),  dim3(1024), 0, stream>>>(u_pk, t_part3);
    kt2b     <<<dim3(32),   dim3(256),  0, stream>>>(t_part3, t);
    kB2      <<<dim3(2048), dim3(256),  0, stream>>>(u_pk, t, bias, s_part);
    k4_squash<<<dim3(16),   dim3(256),  0, stream>>>(s_part, out);
}